// Round 2
// baseline (955.066 us; speedup 1.0000x reference)
//
#include <hip/hip_runtime.h>

#define S_LEN 2048
#define BATCH 64
#define DMODEL 512
#define NHEAD 8
#define HDIM 64
#define LN_EPS_F 1e-5f
#define QSCALE 0.125f  // 1/sqrt(64)
#define NCHUNK 8       // s-chunks of 256; 4 waves/chunk -> 32 wave-chunks
#define NCW 32         // NCHUNK * 4 waves

// ---------------------------------------------------------------------------
// K1: q[b,d] = (src[last_b, b, :] @ Wq^T + bq)*scale for d in [y*256,(y+1)*256)
//     then qk[b,h,:] for heads h in [y*4, y*4+4)
// grid: (B, 2), 256 threads
// ---------------------------------------------------------------------------
__global__ void __launch_bounds__(256) k_q_qk(
    const float* __restrict__ src, const int* __restrict__ seqlen,
    const float* __restrict__ w_in, const float* __restrict__ b_in,
    float* __restrict__ qk)
{
    __shared__ float xl[DMODEL];
    __shared__ float ql[256];
    const int b = blockIdx.x;
    const int y = blockIdx.y;
    const int t = threadIdx.x;
    const int last = seqlen[b] - 1;
    const float* xrow = src + ((size_t)last * BATCH + b) * DMODEL;
    for (int i = t; i < DMODEL; i += 256) xl[i] = xrow[i];
    __syncthreads();
    {
        const int d = y * 256 + t;
        const float* wr = w_in + (size_t)d * DMODEL;
        float acc = b_in[d];
        for (int i = 0; i < DMODEL; i += 4) {
            const float4 r = *reinterpret_cast<const float4*>(wr + i);
            acc += r.x * xl[i] + r.y * xl[i + 1] + r.z * xl[i + 2] + r.w * xl[i + 3];
        }
        ql[t] = acc * QSCALE;
    }
    __syncthreads();
#pragma unroll
    for (int r = 0; r < 8; r++) {
        const int hl = r >> 1;
        const int dp = (r & 1) * 256 + t;
        const int h = y * 4 + hl;
        float acc = 0.f;
#pragma unroll 16
        for (int j = 0; j < HDIM; j++)
            acc += w_in[((size_t)(DMODEL + h * HDIM + j)) * DMODEL + dp] * ql[hl * HDIM + j];
        qk[((size_t)b * NHEAD + h) * DMODEL + dp] = acc;
    }
}

// ---------------------------------------------------------------------------
// K2 (fused scores+softmax+weighted-sum): ONE pass over src.
// grid: (B, NCHUNK), 256 threads = 4 waves. Each wave owns 64 s-rows and is an
// independent softmax chunk (online running max). Per 4-row group:
//   - lane holds src[s_i, b, lane*8 .. +7] in regs (xf)
//   - 32 (h,i) score partials -> 5-stage packed fold + 1 pair-combine:
//     lane ends with full score for (h = lane>>3, i = (lane>>1)&3)
//   - online max update, w = exp(sc - m); weights broadcast via 128B LDS tile
//   - acc[h][k] += w[i][h] * xf[i][k]   (per-lane d-slice accumulators)
// Outputs per wave-chunk cw: xpart[cw][b][h][512], ml[cw][b][h] = (m, l).
// ---------------------------------------------------------------------------
__global__ void __launch_bounds__(256, 2) k_attn(
    const float* __restrict__ src, const float* __restrict__ qk,
    float* __restrict__ xpart, float* __restrict__ ml)
{
    __shared__ float wt[4][32];  // per-wave weight tile [i][h]
    const int b = blockIdx.x;
    const int c = blockIdx.y;
    const int t = threadIdx.x;
    const int wave = t >> 6, lane = t & 63;

    float qr[NHEAD][8];
    const float* qb = qk + (size_t)b * NHEAD * DMODEL + lane * 8;
#pragma unroll
    for (int h = 0; h < NHEAD; h++) {
        const float4 a = *reinterpret_cast<const float4*>(qb + h * DMODEL);
        const float4 d = *reinterpret_cast<const float4*>(qb + h * DMODEL + 4);
        qr[h][0] = a.x; qr[h][1] = a.y; qr[h][2] = a.z; qr[h][3] = a.w;
        qr[h][4] = d.x; qr[h][5] = d.y; qr[h][6] = d.z; qr[h][7] = d.w;
    }
    float acc[NHEAD][8];
#pragma unroll
    for (int h = 0; h < NHEAD; h++)
#pragma unroll
        for (int k = 0; k < 8; k++) acc[h][k] = 0.f;
    float m[NHEAD];
#pragma unroll
    for (int h = 0; h < NHEAD; h++) m[h] = -1e30f;
    float m_own = -1e30f;   // replicates m[lane>>3] without runtime indexing
    float lw = 0.f;         // running sum of w for own (h, i-replica set)
    const int i_own = (lane >> 1) & 3;
    const int sw = c * 256 + wave * 64;

    for (int g = 0; g < 16; g++) {
        float xf[4][8];
#pragma unroll
        for (int i = 0; i < 4; i++) {
            const float* xr = src + ((size_t)(sw + g * 4 + i) * BATCH + b) * DMODEL + lane * 8;
            const float4 xa = *reinterpret_cast<const float4*>(xr);
            const float4 xc = *reinterpret_cast<const float4*>(xr + 4);
            xf[i][0] = xa.x; xf[i][1] = xa.y; xf[i][2] = xa.z; xf[i][3] = xa.w;
            xf[i][4] = xc.x; xf[i][5] = xc.y; xf[i][6] = xc.z; xf[i][7] = xc.w;
        }
        // score partials for 32 (h,i) pairs
        float sc[32];
#pragma unroll
        for (int j = 0; j < 32; j++) {
            const int h = j >> 2, i = j & 3;
            float a = 0.f;
#pragma unroll
            for (int k = 0; k < 8; k++) a += qr[h][k] * xf[i][k];
            sc[j] = a;
        }
        // packed fold: value bit k binds to lane bit k+1; j = lane>>1 afterwards
#pragma unroll
        for (int st = 0; st < 5; st++) {
            const int mk = 32 >> st;
            const int nh = 16 >> st;
            const bool hi = (lane & mk) != 0;
#pragma unroll
            for (int j = 0; j < nh; j++) {
                const float keep = hi ? sc[j + nh] : sc[j];
                const float give = hi ? sc[j] : sc[j + nh];
                sc[j] = keep + __shfl_xor(give, mk, 64);
            }
        }
        const float sfull = sc[0] + __shfl_xor(sc[0], 1, 64);
        // tile max per head: reduce over i (lane bits 1,2)
        float tm = sfull;
        tm = fmaxf(tm, __shfl_xor(tm, 2, 64));
        tm = fmaxf(tm, __shfl_xor(tm, 4, 64));
        // own-head online update
        const float m_own_new = fmaxf(m_own, tm);
        const float fown = __expf(m_own - m_own_new);
        const float w_own = __expf(sfull - m_own_new);
        m_own = m_own_new;
        lw = lw * fown + w_own;
        wt[wave][i_own * 8 + (lane >> 3)] = w_own;  // both bit0-replicas write same value
        // all-head rescale of accumulators
#pragma unroll
        for (int h = 0; h < NHEAD; h++) {
            const float tmh = __shfl(tm, h * 8, 64);
            const float mn = fmaxf(m[h], tmh);
            const float fh = __expf(m[h] - mn);
            m[h] = mn;
#pragma unroll
            for (int k = 0; k < 8; k++) acc[h][k] *= fh;
        }
        // weighted accumulation (weights broadcast from LDS, same-wave ordering)
#pragma unroll
        for (int i = 0; i < 4; i++) {
            const float4 wa = *reinterpret_cast<const float4*>(&wt[wave][i * 8]);
            const float4 wb = *reinterpret_cast<const float4*>(&wt[wave][i * 8 + 4]);
            const float wv[8] = {wa.x, wa.y, wa.z, wa.w, wb.x, wb.y, wb.z, wb.w};
#pragma unroll
            for (int h = 0; h < NHEAD; h++)
#pragma unroll
                for (int k = 0; k < 8; k++) acc[h][k] += wv[h] * xf[i][k];
        }
    }
    // epilogue: per-chunk unnormalized sums + (m, l)
    lw += __shfl_xor(lw, 2, 64);
    lw += __shfl_xor(lw, 4, 64);
    const int cw = c * 4 + wave;
#pragma unroll
    for (int h = 0; h < NHEAD; h++) {
        float* xp = xpart + (((size_t)cw * BATCH + b) * NHEAD + h) * DMODEL + lane * 8;
        *reinterpret_cast<float4*>(xp) = make_float4(acc[h][0], acc[h][1], acc[h][2], acc[h][3]);
        *reinterpret_cast<float4*>(xp + 4) = make_float4(acc[h][4], acc[h][5], acc[h][6], acc[h][7]);
    }
    if ((lane & 7) == 0) {
        const int h = lane >> 3;
        *reinterpret_cast<float2*>(ml + (((size_t)cw * BATCH + b) * NHEAD + h) * 2) =
            make_float2(m_own, lw);
    }
}

// ---------------------------------------------------------------------------
// K3: combine NCW chunks with softmax rescale -> xbar; ctx[e] = Wv[e,:].xbar + bv
// grid: (B, 2), 256 threads; block y covers e in [y*256, y*256+256) = heads y*4..y*4+3
// ---------------------------------------------------------------------------
__global__ void __launch_bounds__(256) k_ctx(
    const float* __restrict__ xpart, const float* __restrict__ ml,
    const float* __restrict__ w_in, const float* __restrict__ b_in,
    float* __restrict__ ctx)
{
    __shared__ float xb[4 * DMODEL];  // 8 KB
    __shared__ float Mh[4], Dn[4];
    __shared__ float coef[4][NCW];
    const int b = blockIdx.x;
    const int y = blockIdx.y;
    const int t = threadIdx.x;
    if (t < 4) {
        const int h = y * 4 + t;
        float M = -1e30f;
#pragma unroll
        for (int cw = 0; cw < NCW; cw++) {
            const float2 v = *reinterpret_cast<const float2*>(
                ml + (((size_t)cw * BATCH + b) * NHEAD + h) * 2);
            M = fmaxf(M, v.x);
        }
        float den = 0.f;
#pragma unroll
        for (int cw = 0; cw < NCW; cw++) {
            const float2 v = *reinterpret_cast<const float2*>(
                ml + (((size_t)cw * BATCH + b) * NHEAD + h) * 2);
            den += __expf(v.x - M) * v.y;
        }
        Mh[t] = M; Dn[t] = den;
    }
    __syncthreads();
    if (t < 4 * NCW) {
        const int h4 = t >> 5, cw = t & (NCW - 1);
        const float2 v = *reinterpret_cast<const float2*>(
            ml + (((size_t)cw * BATCH + b) * NHEAD + y * 4 + h4) * 2);
        coef[h4][cw] = __expf(v.x - Mh[h4]) / Dn[h4];
    }
    __syncthreads();
    for (int i = t; i < 4 * DMODEL; i += 256) {
        const int hl = i >> 9;
        const int d = i & (DMODEL - 1);
        float a = 0.f;
#pragma unroll
        for (int cw = 0; cw < NCW; cw++)
            a += coef[hl][cw] *
                 xpart[(((size_t)cw * BATCH + b) * NHEAD + y * 4 + hl) * DMODEL + d];
        xb[i] = a;
    }
    __syncthreads();
    const int e = y * 256 + t;
    const int hl = t >> 6;
    const float* wr = w_in + ((size_t)(2 * DMODEL + e)) * DMODEL;
    const float* xr = &xb[hl * DMODEL];
    float acc = b_in[2 * DMODEL + e];
    for (int d = 0; d < DMODEL; d += 4) {
        const float4 r = *reinterpret_cast<const float4*>(wr + d);
        acc += r.x * xr[d] + r.y * xr[d + 1] + r.z * xr[d + 2] + r.w * xr[d + 3];
    }
    ctx[(size_t)b * DMODEL + e] = acc;
}

// ---------------------------------------------------------------------------
// K4: attn_out = ctx . Wout^T + bout. grid: (B, 2), 256 threads, 1 output each.
// ---------------------------------------------------------------------------
__global__ void __launch_bounds__(256) k_outproj(
    const float* __restrict__ ctx, const float* __restrict__ w_out,
    const float* __restrict__ b_out, float* __restrict__ attn_out)
{
    __shared__ float cl[DMODEL];
    const int b = blockIdx.x;
    const int y = blockIdx.y;
    const int t = threadIdx.x;
    for (int i = t; i < DMODEL; i += 256) cl[i] = ctx[(size_t)b * DMODEL + i];
    __syncthreads();
    const int o = y * 256 + t;
    const float* wr = w_out + (size_t)o * DMODEL;
    float acc = b_out[o];
    for (int e = 0; e < DMODEL; e += 4) {
        const float4 r = *reinterpret_cast<const float4*>(wr + e);
        acc += r.x * cl[e] + r.y * cl[e + 1] + r.z * cl[e + 2] + r.w * cl[e + 3];
    }
    attn_out[(size_t)b * DMODEL + o] = acc;
}

// ---------------------------------------------------------------------------
// K5: out[s,b,:] = LayerNorm(src[s,b,:] + attn_out[b,:]) * g + beta
// WAVE-PER-ROW: no LDS, no __syncthreads. 8 elems/lane, 12-shuffle butterfly.
// ---------------------------------------------------------------------------
__global__ void __launch_bounds__(256) k_ln(
    const float* __restrict__ src, const float* __restrict__ attn_out,
    const float* __restrict__ g, const float* __restrict__ beta,
    float* __restrict__ out)
{
    const int t = threadIdx.x;
    const int wave = t >> 6, lane = t & 63;
    const int row = blockIdx.x * 4 + wave;  // s*BATCH + b
    const int b = row & (BATCH - 1);
    const int d0 = lane * 8;
    const float* xp = src + (size_t)row * DMODEL + d0;
    const float4 xa = *reinterpret_cast<const float4*>(xp);
    const float4 xc = *reinterpret_cast<const float4*>(xp + 4);
    const float* ap = attn_out + (size_t)b * DMODEL + d0;
    const float4 aa = *reinterpret_cast<const float4*>(ap);
    const float4 ac = *reinterpret_cast<const float4*>(ap + 4);
    float x[8];
    x[0] = xa.x + aa.x; x[1] = xa.y + aa.y; x[2] = xa.z + aa.z; x[3] = xa.w + aa.w;
    x[4] = xc.x + ac.x; x[5] = xc.y + ac.y; x[6] = xc.z + ac.z; x[7] = xc.w + ac.w;
    float s1 = 0.f, s2 = 0.f;
#pragma unroll
    for (int j = 0; j < 8; j++) { s1 += x[j]; s2 += x[j] * x[j]; }
#pragma unroll
    for (int mk = 32; mk; mk >>= 1) {
        s1 += __shfl_xor(s1, mk, 64);
        s2 += __shfl_xor(s2, mk, 64);
    }
    const float mu = s1 * (1.0f / DMODEL);
    const float var = s2 * (1.0f / DMODEL) - mu * mu;
    const float inv = rsqrtf(var + LN_EPS_F);
    const float4 ga = *reinterpret_cast<const float4*>(g + d0);
    const float4 gc = *reinterpret_cast<const float4*>(g + d0 + 4);
    const float4 ba = *reinterpret_cast<const float4*>(beta + d0);
    const float4 bc = *reinterpret_cast<const float4*>(beta + d0 + 4);
    float4 y0, y1;
    y0.x = (x[0] - mu) * inv * ga.x + ba.x;
    y0.y = (x[1] - mu) * inv * ga.y + ba.y;
    y0.z = (x[2] - mu) * inv * ga.z + ba.z;
    y0.w = (x[3] - mu) * inv * ga.w + ba.w;
    y1.x = (x[4] - mu) * inv * gc.x + bc.x;
    y1.y = (x[5] - mu) * inv * gc.y + bc.y;
    y1.z = (x[6] - mu) * inv * gc.z + bc.z;
    y1.w = (x[7] - mu) * inv * gc.w + bc.w;
    float* op = out + (size_t)row * DMODEL + d0;
    *reinterpret_cast<float4*>(op) = y0;
    *reinterpret_cast<float4*>(op + 4) = y1;
}

extern "C" void kernel_launch(void* const* d_in, const int* in_sizes, int n_in,
                              void* d_out, int out_size, void* d_ws, size_t ws_size,
                              hipStream_t stream)
{
    const float* src   = (const float*)d_in[0];
    const int*   slen  = (const int*)d_in[1];
    const float* w_in  = (const float*)d_in[2];
    const float* b_in  = (const float*)d_in[3];
    const float* w_out = (const float*)d_in[4];
    const float* b_out = (const float*)d_in[5];
    const float* g     = (const float*)d_in[6];
    const float* beta  = (const float*)d_in[7];
    float* out = (float*)d_out;

    char* ws = (char*)d_ws;
    float* qk       = (float*)(ws);                       // B*H*D           = 1 MB
    float* xpart    = (float*)(ws + (1u << 20));          // NCW*B*H*D       = 32 MB
    float* ml       = (float*)(ws + 33u * (1u << 20));    // NCW*B*H*2       = 128 KB
    float* ctxbuf   = (float*)(ws + 34u * (1u << 20));    // B*D             = 128 KB
    float* attn_out = (float*)(ws + 35u * (1u << 20));    // B*D             = 128 KB

    k_q_qk<<<dim3(BATCH, 2), 256, 0, stream>>>(src, slen, w_in, b_in, qk);
    k_attn<<<dim3(BATCH, NCHUNK), 256, 0, stream>>>(src, qk, xpart, ml);
    k_ctx<<<dim3(BATCH, 2), 256, 0, stream>>>(xpart, ml, w_in, b_in, ctxbuf);
    k_outproj<<<dim3(BATCH, 2), 256, 0, stream>>>(ctxbuf, w_out, b_out, attn_out);
    k_ln<<<S_LEN * BATCH / 4, 256, 0, stream>>>(src, attn_out, g, beta, out);
}

// Round 3
// 909.820 us; speedup vs baseline: 1.0497x; 1.0497x over previous
//
#include <hip/hip_runtime.h>

#define S_LEN 2048
#define BATCH 64
#define DMODEL 512
#define NHEAD 8
#define HDIM 64
#define LN_EPS_F 1e-5f
#define QSCALE 0.125f  // 1/sqrt(64)
#define NCHUNK 16      // s-chunks of 128 rows; 2 wave-pairs/block -> 32 wave-chunks
#define NCW 32         // NCHUNK * 2 pairs

// ---------------------------------------------------------------------------
// K1: q[b,d] = (src[last_b, b, :] @ Wq^T + bq)*scale for d in [y*256,(y+1)*256)
//     then qk[b,h,:] for heads h in [y*4, y*4+4)
// grid: (B, 2), 256 threads
// ---------------------------------------------------------------------------
__global__ void __launch_bounds__(256) k_q_qk(
    const float* __restrict__ src, const int* __restrict__ seqlen,
    const float* __restrict__ w_in, const float* __restrict__ b_in,
    float* __restrict__ qk)
{
    __shared__ float xl[DMODEL];
    __shared__ float ql[256];
    const int b = blockIdx.x;
    const int y = blockIdx.y;
    const int t = threadIdx.x;
    const int last = seqlen[b] - 1;
    const float* xrow = src + ((size_t)last * BATCH + b) * DMODEL;
    for (int i = t; i < DMODEL; i += 256) xl[i] = xrow[i];
    __syncthreads();
    {
        const int d = y * 256 + t;
        const float* wr = w_in + (size_t)d * DMODEL;
        float acc = b_in[d];
        for (int i = 0; i < DMODEL; i += 4) {
            const float4 r = *reinterpret_cast<const float4*>(wr + i);
            acc += r.x * xl[i] + r.y * xl[i + 1] + r.z * xl[i + 2] + r.w * xl[i + 3];
        }
        ql[t] = acc * QSCALE;
    }
    __syncthreads();
#pragma unroll
    for (int r = 0; r < 8; r++) {
        const int hl = r >> 1;
        const int dp = (r & 1) * 256 + t;
        const int h = y * 4 + hl;
        float acc = 0.f;
#pragma unroll 16
        for (int j = 0; j < HDIM; j++)
            acc += w_in[((size_t)(DMODEL + h * HDIM + j)) * DMODEL + dp] * ql[hl * HDIM + j];
        qk[((size_t)b * NHEAD + h) * DMODEL + dp] = acc;
    }
}

// ---------------------------------------------------------------------------
// K2 (fused scores+softmax+weighted-sum): ONE pass over src, spill-free.
// grid: (B, NCHUNK), 256 threads = 4 waves = 2 wave-PAIRS.
// Pair p = {wave 2p, wave 2p+1} covers rows [c*128 + p*64, +64); even wave
// handles heads 0-3, odd wave heads 4-7 (duplicate src loads hit L1/L2).
// Per wave, per 4-row group:
//   - xf[4][8]: lane's 32B d-slice of 4 rows (registers)
//   - 16 (hl,i) score partials -> 4-stage packed fold + 2-combine tail:
//     lane ends with full score for hl=(lane>>4)&3, i=(lane>>2)&3
//   - exact online max: acc rescale ONLY on record-break (wave-uniform branch)
//   - weights broadcast via 64B/wave LDS tile; acc[hl][k] += w[i][hl]*xf[i][k]
// Outputs per wave-chunk cw = c*2+p: xpart[cw][b][h][512], ml[cw][b][h]=(m,l).
// ---------------------------------------------------------------------------
__global__ void __launch_bounds__(256, 3) k_attn(
    const float* __restrict__ src, const float* __restrict__ qk,
    float* __restrict__ xpart, float* __restrict__ ml)
{
    __shared__ float wt[4][4][4];  // [wave][i][hl]
    const int b = blockIdx.x;
    const int c = blockIdx.y;
    const int t = threadIdx.x;
    const int wave = t >> 6, lane = t & 63;
    const int hbase = (wave & 1) * 4;

    float qr[4][8];
    const float* qb = qk + ((size_t)b * NHEAD + hbase) * DMODEL + lane * 8;
#pragma unroll
    for (int hl = 0; hl < 4; hl++) {
        const float4 a = *reinterpret_cast<const float4*>(qb + hl * DMODEL);
        const float4 d = *reinterpret_cast<const float4*>(qb + hl * DMODEL + 4);
        qr[hl][0] = a.x; qr[hl][1] = a.y; qr[hl][2] = a.z; qr[hl][3] = a.w;
        qr[hl][4] = d.x; qr[hl][5] = d.y; qr[hl][6] = d.z; qr[hl][7] = d.w;
    }
    float acc[4][8];
#pragma unroll
    for (int hl = 0; hl < 4; hl++)
#pragma unroll
        for (int k = 0; k < 8; k++) acc[hl][k] = 0.f;
    float m[4] = {-1e30f, -1e30f, -1e30f, -1e30f};
    float m_own = -1e30f;  // == m[own head] (lane's own head: (lane>>4)&3)
    float lw = 0.f;
    const int i_own = (lane >> 2) & 3;
    const int hl_own = (lane >> 4) & 3;
    const int sw = c * 128 + (wave >> 1) * 64;

    for (int g = 0; g < 16; g++) {
        float xf[4][8];
#pragma unroll
        for (int i = 0; i < 4; i++) {
            const float* xr = src + ((size_t)(sw + g * 4 + i) * BATCH + b) * DMODEL + lane * 8;
            const float4 xa = *reinterpret_cast<const float4*>(xr);
            const float4 xc = *reinterpret_cast<const float4*>(xr + 4);
            xf[i][0] = xa.x; xf[i][1] = xa.y; xf[i][2] = xa.z; xf[i][3] = xa.w;
            xf[i][4] = xc.x; xf[i][5] = xc.y; xf[i][6] = xc.z; xf[i][7] = xc.w;
        }
        // 16 score partials: j = hl*4 + i
        float sc[16];
#pragma unroll
        for (int j = 0; j < 16; j++) {
            const int hl = j >> 2, i = j & 3;
            float a = 0.f;
#pragma unroll
            for (int k = 0; k < 8; k++) a += qr[hl][k] * xf[i][k];
            sc[j] = a;
        }
        // packed fold: value bit 3..0 binds to lane bit 5..2
#pragma unroll
        for (int st = 0; st < 4; st++) {
            const int mk = 32 >> st;
            const int nh = 8 >> st;
            const bool hi = (lane & mk) != 0;
#pragma unroll
            for (int j = 0; j < nh; j++) {
                const float keep = hi ? sc[j + nh] : sc[j];
                const float give = hi ? sc[j] : sc[j + nh];
                sc[j] = keep + __shfl_xor(give, mk, 64);
            }
        }
        float sfull = sc[0];
        sfull += __shfl_xor(sfull, 2, 64);
        sfull += __shfl_xor(sfull, 1, 64);
        // tile max per head: reduce over i (lane bits 3,2)
        float tm = sfull;
        tm = fmaxf(tm, __shfl_xor(tm, 8, 64));
        tm = fmaxf(tm, __shfl_xor(tm, 4, 64));
        // per-lane online update for own head (exact; factor==1 when no record)
        const float m_new = fmaxf(m_own, tm);
        lw *= __expf(m_own - m_new);
        m_own = m_new;
        const float w = __expf(sfull - m_own);
        lw += w;
        wt[wave][i_own][hl_own] = w;  // 4 replicas write identical value
        // per-head rescale ONLY on record-break (wave-uniform branch)
#pragma unroll
        for (int hl = 0; hl < 4; hl++) {
            const float tmh = __shfl(tm, hl << 4, 64);
            if (tmh > m[hl]) {
                const float f = __expf(m[hl] - tmh);
#pragma unroll
                for (int k = 0; k < 8; k++) acc[hl][k] *= f;
                m[hl] = tmh;
            }
        }
        // weighted accumulation (weights broadcast from own wave's LDS tile)
#pragma unroll
        for (int i = 0; i < 4; i++) {
            const float4 w4 = *reinterpret_cast<const float4*>(&wt[wave][i][0]);
            const float wv[4] = {w4.x, w4.y, w4.z, w4.w};
#pragma unroll
            for (int hl = 0; hl < 4; hl++)
#pragma unroll
                for (int k = 0; k < 8; k++) acc[hl][k] += wv[hl] * xf[i][k];
        }
    }
    // epilogue: per-chunk unnormalized sums + (m, l)
    lw += __shfl_xor(lw, 4, 64);
    lw += __shfl_xor(lw, 8, 64);
    const int cw = c * 2 + (wave >> 1);
#pragma unroll
    for (int hl = 0; hl < 4; hl++) {
        float* xp = xpart + (((size_t)cw * BATCH + b) * NHEAD + hbase + hl) * DMODEL + lane * 8;
        *reinterpret_cast<float4*>(xp) = make_float4(acc[hl][0], acc[hl][1], acc[hl][2], acc[hl][3]);
        *reinterpret_cast<float4*>(xp + 4) = make_float4(acc[hl][4], acc[hl][5], acc[hl][6], acc[hl][7]);
    }
    if ((lane & 15) == 0) {
        const int hl = lane >> 4;
        *reinterpret_cast<float2*>(ml + (((size_t)cw * BATCH + b) * NHEAD + hbase + hl) * 2) =
            make_float2(m_own, lw);
    }
}

// ---------------------------------------------------------------------------
// K3: combine NCW chunks with softmax rescale -> xbar; ctx[e] = Wv[e,:].xbar + bv
// grid: (B, 2), 256 threads; block y covers e in [y*256, y*256+256) = heads y*4..y*4+3
// ---------------------------------------------------------------------------
__global__ void __launch_bounds__(256) k_ctx(
    const float* __restrict__ xpart, const float* __restrict__ ml,
    const float* __restrict__ w_in, const float* __restrict__ b_in,
    float* __restrict__ ctx)
{
    __shared__ float xb[4 * DMODEL];  // 8 KB
    __shared__ float Mh[4], Dn[4];
    __shared__ float coef[4][NCW];
    const int b = blockIdx.x;
    const int y = blockIdx.y;
    const int t = threadIdx.x;
    if (t < 4) {
        const int h = y * 4 + t;
        float M = -1e30f;
#pragma unroll
        for (int cw = 0; cw < NCW; cw++) {
            const float2 v = *reinterpret_cast<const float2*>(
                ml + (((size_t)cw * BATCH + b) * NHEAD + h) * 2);
            M = fmaxf(M, v.x);
        }
        float den = 0.f;
#pragma unroll
        for (int cw = 0; cw < NCW; cw++) {
            const float2 v = *reinterpret_cast<const float2*>(
                ml + (((size_t)cw * BATCH + b) * NHEAD + h) * 2);
            den += __expf(v.x - M) * v.y;
        }
        Mh[t] = M; Dn[t] = den;
    }
    __syncthreads();
    if (t < 4 * NCW) {
        const int h4 = t >> 5, cw = t & (NCW - 1);
        const float2 v = *reinterpret_cast<const float2*>(
            ml + (((size_t)cw * BATCH + b) * NHEAD + y * 4 + h4) * 2);
        coef[h4][cw] = __expf(v.x - Mh[h4]) / Dn[h4];
    }
    __syncthreads();
    for (int i = t; i < 4 * DMODEL; i += 256) {
        const int hl = i >> 9;
        const int d = i & (DMODEL - 1);
        float a = 0.f;
#pragma unroll
        for (int cw = 0; cw < NCW; cw++)
            a += coef[hl][cw] *
                 xpart[(((size_t)cw * BATCH + b) * NHEAD + y * 4 + hl) * DMODEL + d];
        xb[i] = a;
    }
    __syncthreads();
    const int e = y * 256 + t;
    const int hl = t >> 6;
    const float* wr = w_in + ((size_t)(2 * DMODEL + e)) * DMODEL;
    const float* xr = &xb[hl * DMODEL];
    float acc = b_in[2 * DMODEL + e];
    for (int d = 0; d < DMODEL; d += 4) {
        const float4 r = *reinterpret_cast<const float4*>(wr + d);
        acc += r.x * xr[d] + r.y * xr[d + 1] + r.z * xr[d + 2] + r.w * xr[d + 3];
    }
    ctx[(size_t)b * DMODEL + e] = acc;
}

// ---------------------------------------------------------------------------
// K4: attn_out = ctx . Wout^T + bout. grid: (B, 2), 256 threads, 1 output each.
// ---------------------------------------------------------------------------
__global__ void __launch_bounds__(256) k_outproj(
    const float* __restrict__ ctx, const float* __restrict__ w_out,
    const float* __restrict__ b_out, float* __restrict__ attn_out)
{
    __shared__ float cl[DMODEL];
    const int b = blockIdx.x;
    const int y = blockIdx.y;
    const int t = threadIdx.x;
    for (int i = t; i < DMODEL; i += 256) cl[i] = ctx[(size_t)b * DMODEL + i];
    __syncthreads();
    const int o = y * 256 + t;
    const float* wr = w_out + (size_t)o * DMODEL;
    float acc = b_out[o];
    for (int e = 0; e < DMODEL; e += 4) {
        const float4 r = *reinterpret_cast<const float4*>(wr + e);
        acc += r.x * cl[e] + r.y * cl[e + 1] + r.z * cl[e + 2] + r.w * cl[e + 3];
    }
    attn_out[(size_t)b * DMODEL + o] = acc;
}

// ---------------------------------------------------------------------------
// K5: out[s,b,:] = LayerNorm(src[s,b,:] + attn_out[b,:]) * g + beta
// WAVE-PER-ROW: no LDS, no __syncthreads. 8 elems/lane, 12-shuffle butterfly.
// ---------------------------------------------------------------------------
__global__ void __launch_bounds__(256) k_ln(
    const float* __restrict__ src, const float* __restrict__ attn_out,
    const float* __restrict__ g, const float* __restrict__ beta,
    float* __restrict__ out)
{
    const int t = threadIdx.x;
    const int wave = t >> 6, lane = t & 63;
    const int row = blockIdx.x * 4 + wave;  // s*BATCH + b
    const int b = row & (BATCH - 1);
    const int d0 = lane * 8;
    const float* xp = src + (size_t)row * DMODEL + d0;
    const float4 xa = *reinterpret_cast<const float4*>(xp);
    const float4 xc = *reinterpret_cast<const float4*>(xp + 4);
    const float* ap = attn_out + (size_t)b * DMODEL + d0;
    const float4 aa = *reinterpret_cast<const float4*>(ap);
    const float4 ac = *reinterpret_cast<const float4*>(ap + 4);
    float x[8];
    x[0] = xa.x + aa.x; x[1] = xa.y + aa.y; x[2] = xa.z + aa.z; x[3] = xa.w + aa.w;
    x[4] = xc.x + ac.x; x[5] = xc.y + ac.y; x[6] = xc.z + ac.z; x[7] = xc.w + ac.w;
    float s1 = 0.f, s2 = 0.f;
#pragma unroll
    for (int j = 0; j < 8; j++) { s1 += x[j]; s2 += x[j] * x[j]; }
#pragma unroll
    for (int mk = 32; mk; mk >>= 1) {
        s1 += __shfl_xor(s1, mk, 64);
        s2 += __shfl_xor(s2, mk, 64);
    }
    const float mu = s1 * (1.0f / DMODEL);
    const float var = s2 * (1.0f / DMODEL) - mu * mu;
    const float inv = rsqrtf(var + LN_EPS_F);
    const float4 ga = *reinterpret_cast<const float4*>(g + d0);
    const float4 gc = *reinterpret_cast<const float4*>(g + d0 + 4);
    const float4 ba = *reinterpret_cast<const float4*>(beta + d0);
    const float4 bc = *reinterpret_cast<const float4*>(beta + d0 + 4);
    float4 y0, y1;
    y0.x = (x[0] - mu) * inv * ga.x + ba.x;
    y0.y = (x[1] - mu) * inv * ga.y + ba.y;
    y0.z = (x[2] - mu) * inv * ga.z + ba.z;
    y0.w = (x[3] - mu) * inv * ga.w + ba.w;
    y1.x = (x[4] - mu) * inv * gc.x + bc.x;
    y1.y = (x[5] - mu) * inv * gc.y + bc.y;
    y1.z = (x[6] - mu) * inv * gc.z + bc.z;
    y1.w = (x[7] - mu) * inv * gc.w + bc.w;
    float* op = out + (size_t)row * DMODEL + d0;
    *reinterpret_cast<float4*>(op) = y0;
    *reinterpret_cast<float4*>(op + 4) = y1;
}

extern "C" void kernel_launch(void* const* d_in, const int* in_sizes, int n_in,
                              void* d_out, int out_size, void* d_ws, size_t ws_size,
                              hipStream_t stream)
{
    const float* src   = (const float*)d_in[0];
    const int*   slen  = (const int*)d_in[1];
    const float* w_in  = (const float*)d_in[2];
    const float* b_in  = (const float*)d_in[3];
    const float* w_out = (const float*)d_in[4];
    const float* b_out = (const float*)d_in[5];
    const float* g     = (const float*)d_in[6];
    const float* beta  = (const float*)d_in[7];
    float* out = (float*)d_out;

    char* ws = (char*)d_ws;
    float* qk       = (float*)(ws);                       // B*H*D           = 1 MB
    float* xpart    = (float*)(ws + (1u << 20));          // NCW*B*H*D       = 32 MB
    float* ml       = (float*)(ws + 33u * (1u << 20));    // NCW*B*H*2       = 128 KB
    float* ctxbuf   = (float*)(ws + 34u * (1u << 20));    // B*D             = 128 KB
    float* attn_out = (float*)(ws + 35u * (1u << 20));    // B*D             = 128 KB

    k_q_qk<<<dim3(BATCH, 2), 256, 0, stream>>>(src, slen, w_in, b_in, qk);
    k_attn<<<dim3(BATCH, NCHUNK), 256, 0, stream>>>(src, qk, xpart, ml);
    k_ctx<<<dim3(BATCH, 2), 256, 0, stream>>>(xpart, ml, w_in, b_in, ctxbuf);
    k_outproj<<<dim3(BATCH, 2), 256, 0, stream>>>(ctxbuf, w_out, b_out, attn_out);
    k_ln<<<S_LEN * BATCH / 4, 256, 0, stream>>>(src, attn_out, g, beta, out);
}

// Round 4
// 621.284 us; speedup vs baseline: 1.5372x; 1.4644x over previous
//
#include <hip/hip_runtime.h>

#define S_LEN 2048
#define BATCH 64
#define DMODEL 512
#define NHEAD 8
#define HDIM 64
#define LN_EPS_F 1e-5f
#define QSCALE 0.125f  // 1/sqrt(64)
#define NCHUNK 16      // s-chunks of 128 rows; 2 wave-pairs/block -> 32 wave-chunks
#define NCW 32         // NCHUNK * 2 pairs

// ---------------------------------------------------------------------------
// K1: q[b,d] = (src[last_b, b, :] @ Wq^T + bq)*scale for d in [y*256,(y+1)*256)
//     then qk[b,h,:] for heads h in [y*4, y*4+4)
// grid: (B, 2), 256 threads
// ---------------------------------------------------------------------------
__global__ void __launch_bounds__(256) k_q_qk(
    const float* __restrict__ src, const int* __restrict__ seqlen,
    const float* __restrict__ w_in, const float* __restrict__ b_in,
    float* __restrict__ qk)
{
    __shared__ float xl[DMODEL];
    __shared__ float ql[256];
    const int b = blockIdx.x;
    const int y = blockIdx.y;
    const int t = threadIdx.x;
    const int last = seqlen[b] - 1;
    const float* xrow = src + ((size_t)last * BATCH + b) * DMODEL;
    for (int i = t; i < DMODEL; i += 256) xl[i] = xrow[i];
    __syncthreads();
    {
        const int d = y * 256 + t;
        const float* wr = w_in + (size_t)d * DMODEL;
        float acc = b_in[d];
        for (int i = 0; i < DMODEL; i += 4) {
            const float4 r = *reinterpret_cast<const float4*>(wr + i);
            acc += r.x * xl[i] + r.y * xl[i + 1] + r.z * xl[i + 2] + r.w * xl[i + 3];
        }
        ql[t] = acc * QSCALE;
    }
    __syncthreads();
#pragma unroll
    for (int r = 0; r < 8; r++) {
        const int hl = r >> 1;
        const int dp = (r & 1) * 256 + t;
        const int h = y * 4 + hl;
        float acc = 0.f;
#pragma unroll 16
        for (int j = 0; j < HDIM; j++)
            acc += w_in[((size_t)(DMODEL + h * HDIM + j)) * DMODEL + dp] * ql[hl * HDIM + j];
        qk[((size_t)b * NHEAD + h) * DMODEL + dp] = acc;
    }
}

// ---------------------------------------------------------------------------
// K2 (fused scores+softmax+weighted-sum): ONE pass over src.
// grid: (B, NCHUNK), 256 threads = 4 waves = 2 wave-PAIRS.
// Pair p covers rows [c*128 + p*64, +64); even wave heads 0-3, odd wave 4-7.
// The 16-value cross-lane fold is MANUALLY EXPANDED (literal indices only) so
// no array can be demoted to scratch (round-2/3 lesson: runtime-indexed
// arrays -> local memory -> 700 MB of scratch traffic).
// ---------------------------------------------------------------------------
#define FOLD1(A, B, HI, MK)                                        \
    {                                                              \
        const float keep_ = (HI) ? (B) : (A);                      \
        const float give_ = (HI) ? (A) : (B);                      \
        (A) = keep_ + __shfl_xor(give_, MK, 64);                   \
    }

__global__ void __launch_bounds__(256, 3) k_attn(
    const float* __restrict__ src, const float* __restrict__ qk,
    float* __restrict__ xpart, float* __restrict__ ml)
{
    __shared__ float wt[4][4][4];  // [wave][i][hl]
    const int b = blockIdx.x;
    const int c = blockIdx.y;
    const int t = threadIdx.x;
    const int wave = t >> 6, lane = t & 63;
    const int hbase = (wave & 1) * 4;

    float qr[4][8];
    const float* qb = qk + ((size_t)b * NHEAD + hbase) * DMODEL + lane * 8;
#pragma unroll
    for (int hl = 0; hl < 4; hl++) {
        const float4 a = *reinterpret_cast<const float4*>(qb + hl * DMODEL);
        const float4 d = *reinterpret_cast<const float4*>(qb + hl * DMODEL + 4);
        qr[hl][0] = a.x; qr[hl][1] = a.y; qr[hl][2] = a.z; qr[hl][3] = a.w;
        qr[hl][4] = d.x; qr[hl][5] = d.y; qr[hl][6] = d.z; qr[hl][7] = d.w;
    }
    float acc[4][8];
#pragma unroll
    for (int hl = 0; hl < 4; hl++)
#pragma unroll
        for (int k = 0; k < 8; k++) acc[hl][k] = 0.f;
    float m[4] = {-1e30f, -1e30f, -1e30f, -1e30f};
    float m_own = -1e30f;
    float lw = 0.f;
    const int i_own = (lane >> 2) & 3;
    const int hl_own = (lane >> 4) & 3;
    const bool h32 = (lane & 32) != 0;
    const bool h16 = (lane & 16) != 0;
    const bool h8 = (lane & 8) != 0;
    const bool h4 = (lane & 4) != 0;
    const int sw = c * 128 + (wave >> 1) * 64;

    for (int g = 0; g < 16; g++) {
        float xf[4][8];
#pragma unroll
        for (int i = 0; i < 4; i++) {
            const float* xr = src + ((size_t)(sw + g * 4 + i) * BATCH + b) * DMODEL + lane * 8;
            const float4 xa = *reinterpret_cast<const float4*>(xr);
            const float4 xc = *reinterpret_cast<const float4*>(xr + 4);
            xf[i][0] = xa.x; xf[i][1] = xa.y; xf[i][2] = xa.z; xf[i][3] = xa.w;
            xf[i][4] = xc.x; xf[i][5] = xc.y; xf[i][6] = xc.z; xf[i][7] = xc.w;
        }
        // 16 score partials: j = hl*4 + i (all indices literal after unroll)
        float sc[16];
#pragma unroll
        for (int hl = 0; hl < 4; hl++)
#pragma unroll
            for (int i = 0; i < 4; i++) {
                float a = 0.f;
#pragma unroll
                for (int k = 0; k < 8; k++) a += qr[hl][k] * xf[i][k];
                sc[hl * 4 + i] = a;
            }
        // packed fold, manually expanded: value bit 3..0 binds lane bit 5..2.
        // stage mk=32 (value bit 3):
        FOLD1(sc[0], sc[8], h32, 32)  FOLD1(sc[1], sc[9], h32, 32)
        FOLD1(sc[2], sc[10], h32, 32) FOLD1(sc[3], sc[11], h32, 32)
        FOLD1(sc[4], sc[12], h32, 32) FOLD1(sc[5], sc[13], h32, 32)
        FOLD1(sc[6], sc[14], h32, 32) FOLD1(sc[7], sc[15], h32, 32)
        // stage mk=16 (value bit 2):
        FOLD1(sc[0], sc[4], h16, 16)  FOLD1(sc[1], sc[5], h16, 16)
        FOLD1(sc[2], sc[6], h16, 16)  FOLD1(sc[3], sc[7], h16, 16)
        // stage mk=8 (value bit 1):
        FOLD1(sc[0], sc[2], h8, 8)    FOLD1(sc[1], sc[3], h8, 8)
        // stage mk=4 (value bit 0):
        FOLD1(sc[0], sc[1], h4, 4)
        float sfull = sc[0];
        sfull += __shfl_xor(sfull, 2, 64);
        sfull += __shfl_xor(sfull, 1, 64);
        // tile max per head: reduce over i (lane bits 3,2)
        float tm = sfull;
        tm = fmaxf(tm, __shfl_xor(tm, 8, 64));
        tm = fmaxf(tm, __shfl_xor(tm, 4, 64));
        // own-head online update (exact; factor==1 when no record)
        const float m_new = fmaxf(m_own, tm);
        lw *= __expf(m_own - m_new);
        m_own = m_new;
        const float w = __expf(sfull - m_own);
        lw += w;
        wt[wave][i_own][hl_own] = w;  // 4 replicas write identical value
        // per-head rescale ONLY on record-break (wave-uniform branch)
#pragma unroll
        for (int hl = 0; hl < 4; hl++) {
            const float tmh = __shfl(tm, hl << 4, 64);
            if (tmh > m[hl]) {
                const float f = __expf(m[hl] - tmh);
#pragma unroll
                for (int k = 0; k < 8; k++) acc[hl][k] *= f;
                m[hl] = tmh;
            }
        }
        // weighted accumulation (weights broadcast from own wave's LDS tile)
#pragma unroll
        for (int i = 0; i < 4; i++) {
            const float4 w4 = *reinterpret_cast<const float4*>(&wt[wave][i][0]);
#pragma unroll
            for (int k = 0; k < 8; k++) {
                acc[0][k] += w4.x * xf[i][k];
                acc[1][k] += w4.y * xf[i][k];
                acc[2][k] += w4.z * xf[i][k];
                acc[3][k] += w4.w * xf[i][k];
            }
        }
    }
    // epilogue: per-chunk unnormalized sums + (m, l)
    lw += __shfl_xor(lw, 4, 64);
    lw += __shfl_xor(lw, 8, 64);
    const int cw = c * 2 + (wave >> 1);
#pragma unroll
    for (int hl = 0; hl < 4; hl++) {
        float* xp = xpart + (((size_t)cw * BATCH + b) * NHEAD + hbase + hl) * DMODEL + lane * 8;
        *reinterpret_cast<float4*>(xp) = make_float4(acc[hl][0], acc[hl][1], acc[hl][2], acc[hl][3]);
        *reinterpret_cast<float4*>(xp + 4) = make_float4(acc[hl][4], acc[hl][5], acc[hl][6], acc[hl][7]);
    }
    if ((lane & 15) == 0) {
        const int hl = lane >> 4;
        *reinterpret_cast<float2*>(ml + (((size_t)cw * BATCH + b) * NHEAD + hbase + hl) * 2) =
            make_float2(m_own, lw);
    }
}

// ---------------------------------------------------------------------------
// K3: combine NCW chunks with softmax rescale -> xbar; ctx[e] = Wv[e,:].xbar + bv
// grid: (B, 2), 256 threads; block y covers e in [y*256, y*256+256) = heads y*4..y*4+3
// ---------------------------------------------------------------------------
__global__ void __launch_bounds__(256) k_ctx(
    const float* __restrict__ xpart, const float* __restrict__ ml,
    const float* __restrict__ w_in, const float* __restrict__ b_in,
    float* __restrict__ ctx)
{
    __shared__ float xb[4 * DMODEL];  // 8 KB
    __shared__ float Mh[4], Dn[4];
    __shared__ float coef[4][NCW];
    const int b = blockIdx.x;
    const int y = blockIdx.y;
    const int t = threadIdx.x;
    if (t < 4) {
        const int h = y * 4 + t;
        float M = -1e30f;
#pragma unroll
        for (int cw = 0; cw < NCW; cw++) {
            const float2 v = *reinterpret_cast<const float2*>(
                ml + (((size_t)cw * BATCH + b) * NHEAD + h) * 2);
            M = fmaxf(M, v.x);
        }
        float den = 0.f;
#pragma unroll
        for (int cw = 0; cw < NCW; cw++) {
            const float2 v = *reinterpret_cast<const float2*>(
                ml + (((size_t)cw * BATCH + b) * NHEAD + h) * 2);
            den += __expf(v.x - M) * v.y;
        }
        Mh[t] = M; Dn[t] = den;
    }
    __syncthreads();
    if (t < 4 * NCW) {
        const int h4 = t >> 5, cw = t & (NCW - 1);
        const float2 v = *reinterpret_cast<const float2*>(
            ml + (((size_t)cw * BATCH + b) * NHEAD + y * 4 + h4) * 2);
        coef[h4][cw] = __expf(v.x - Mh[h4]) / Dn[h4];
    }
    __syncthreads();
    for (int i = t; i < 4 * DMODEL; i += 256) {
        const int hl = i >> 9;
        const int d = i & (DMODEL - 1);
        float a = 0.f;
#pragma unroll
        for (int cw = 0; cw < NCW; cw++)
            a += coef[hl][cw] *
                 xpart[(((size_t)cw * BATCH + b) * NHEAD + y * 4 + hl) * DMODEL + d];
        xb[i] = a;
    }
    __syncthreads();
    const int e = y * 256 + t;
    const int hl = t >> 6;
    const float* wr = w_in + ((size_t)(2 * DMODEL + e)) * DMODEL;
    const float* xr = &xb[hl * DMODEL];
    float acc = b_in[2 * DMODEL + e];
    for (int d = 0; d < DMODEL; d += 4) {
        const float4 r = *reinterpret_cast<const float4*>(wr + d);
        acc += r.x * xr[d] + r.y * xr[d + 1] + r.z * xr[d + 2] + r.w * xr[d + 3];
    }
    ctx[(size_t)b * DMODEL + e] = acc;
}

// ---------------------------------------------------------------------------
// K4: attn_out = ctx . Wout^T + bout. grid: (B, 2), 256 threads, 1 output each.
// ---------------------------------------------------------------------------
__global__ void __launch_bounds__(256) k_outproj(
    const float* __restrict__ ctx, const float* __restrict__ w_out,
    const float* __restrict__ b_out, float* __restrict__ attn_out)
{
    __shared__ float cl[DMODEL];
    const int b = blockIdx.x;
    const int y = blockIdx.y;
    const int t = threadIdx.x;
    for (int i = t; i < DMODEL; i += 256) cl[i] = ctx[(size_t)b * DMODEL + i];
    __syncthreads();
    const int o = y * 256 + t;
    const float* wr = w_out + (size_t)o * DMODEL;
    float acc = b_out[o];
    for (int e = 0; e < DMODEL; e += 4) {
        const float4 r = *reinterpret_cast<const float4*>(wr + e);
        acc += r.x * cl[e] + r.y * cl[e + 1] + r.z * cl[e + 2] + r.w * cl[e + 3];
    }
    attn_out[(size_t)b * DMODEL + o] = acc;
}

// ---------------------------------------------------------------------------
// K5: out[s,b,:] = LayerNorm(src[s,b,:] + attn_out[b,:]) * g + beta
// WAVE-PER-ROW: no LDS, no __syncthreads. 8 elems/lane, 12-shuffle butterfly.
// ---------------------------------------------------------------------------
__global__ void __launch_bounds__(256) k_ln(
    const float* __restrict__ src, const float* __restrict__ attn_out,
    const float* __restrict__ g, const float* __restrict__ beta,
    float* __restrict__ out)
{
    const int t = threadIdx.x;
    const int wave = t >> 6, lane = t & 63;
    const int row = blockIdx.x * 4 + wave;  // s*BATCH + b
    const int b = row & (BATCH - 1);
    const int d0 = lane * 8;
    const float* xp = src + (size_t)row * DMODEL + d0;
    const float4 xa = *reinterpret_cast<const float4*>(xp);
    const float4 xc = *reinterpret_cast<const float4*>(xp + 4);
    const float* ap = attn_out + (size_t)b * DMODEL + d0;
    const float4 aa = *reinterpret_cast<const float4*>(ap);
    const float4 ac = *reinterpret_cast<const float4*>(ap + 4);
    float x[8];
    x[0] = xa.x + aa.x; x[1] = xa.y + aa.y; x[2] = xa.z + aa.z; x[3] = xa.w + aa.w;
    x[4] = xc.x + ac.x; x[5] = xc.y + ac.y; x[6] = xc.z + ac.z; x[7] = xc.w + ac.w;
    float s1 = 0.f, s2 = 0.f;
#pragma unroll
    for (int j = 0; j < 8; j++) { s1 += x[j]; s2 += x[j] * x[j]; }
#pragma unroll
    for (int mk = 32; mk; mk >>= 1) {
        s1 += __shfl_xor(s1, mk, 64);
        s2 += __shfl_xor(s2, mk, 64);
    }
    const float mu = s1 * (1.0f / DMODEL);
    const float var = s2 * (1.0f / DMODEL) - mu * mu;
    const float inv = rsqrtf(var + LN_EPS_F);
    const float4 ga = *reinterpret_cast<const float4*>(g + d0);
    const float4 gc = *reinterpret_cast<const float4*>(g + d0 + 4);
    const float4 ba = *reinterpret_cast<const float4*>(beta + d0);
    const float4 bc = *reinterpret_cast<const float4*>(beta + d0 + 4);
    float4 y0, y1;
    y0.x = (x[0] - mu) * inv * ga.x + ba.x;
    y0.y = (x[1] - mu) * inv * ga.y + ba.y;
    y0.z = (x[2] - mu) * inv * ga.z + ba.z;
    y0.w = (x[3] - mu) * inv * ga.w + ba.w;
    y1.x = (x[4] - mu) * inv * gc.x + bc.x;
    y1.y = (x[5] - mu) * inv * gc.y + bc.y;
    y1.z = (x[6] - mu) * inv * gc.z + bc.z;
    y1.w = (x[7] - mu) * inv * gc.w + bc.w;
    float* op = out + (size_t)row * DMODEL + d0;
    *reinterpret_cast<float4*>(op) = y0;
    *reinterpret_cast<float4*>(op + 4) = y1;
}

extern "C" void kernel_launch(void* const* d_in, const int* in_sizes, int n_in,
                              void* d_out, int out_size, void* d_ws, size_t ws_size,
                              hipStream_t stream)
{
    const float* src   = (const float*)d_in[0];
    const int*   slen  = (const int*)d_in[1];
    const float* w_in  = (const float*)d_in[2];
    const float* b_in  = (const float*)d_in[3];
    const float* w_out = (const float*)d_in[4];
    const float* b_out = (const float*)d_in[5];
    const float* g     = (const float*)d_in[6];
    const float* beta  = (const float*)d_in[7];
    float* out = (float*)d_out;

    char* ws = (char*)d_ws;
    float* qk       = (float*)(ws);                       // B*H*D           = 1 MB
    float* xpart    = (float*)(ws + (1u << 20));          // NCW*B*H*D       = 32 MB
    float* ml       = (float*)(ws + 33u * (1u << 20));    // NCW*B*H*2       = 128 KB
    float* ctxbuf   = (float*)(ws + 34u * (1u << 20));    // B*D             = 128 KB
    float* attn_out = (float*)(ws + 35u * (1u << 20));    // B*D             = 128 KB

    k_q_qk<<<dim3(BATCH, 2), 256, 0, stream>>>(src, slen, w_in, b_in, qk);
    k_attn<<<dim3(BATCH, NCHUNK), 256, 0, stream>>>(src, qk, xpart, ml);
    k_ctx<<<dim3(BATCH, 2), 256, 0, stream>>>(xpart, ml, w_in, b_in, ctxbuf);
    k_outproj<<<dim3(BATCH, 2), 256, 0, stream>>>(ctxbuf, w_out, b_out, attn_out);
    k_ln<<<S_LEN * BATCH / 4, 256, 0, stream>>>(src, attn_out, g, beta, out);
}